// Round 10
// baseline (502.598 us; speedup 1.0000x reference)
//
#include <hip/hip_runtime.h>

#define NN  100000
#define SEQ 12

typedef float f32x2 __attribute__((ext_vector_type(2)));
typedef float f32x4 __attribute__((ext_vector_type(4)));

// d_ws float offsets (repacked weights; mirrored 1:1 into LDS)
#define OFF_UV   0        // [32][8]: k*8 + {u_i,u_f,u_g,u_o, v_i,v_f,v_g,v_o}
#define OFF_W0   256      // [16][8][32]:  (wave, j4, u*16+g*4+jj)  layer-0 Whh, wave owns 2 units
#define OFF_W1   4352     // [16][16][32]: (wave, j4, u*16+g*4+jj)  [Wih1|Whh1]
#define OFF_B1   12544    // [32][4]       bih1+bhh1
#define OFF_FC1  12672    // [16][32]      W_fc1 transposed
#define OFF_BFC1 13184    // [16]
#define OFF_FC2  13200    // [16]
#define OFF_BFC2 13216    // [1]
#define W_TOTAL  13217

__device__ __forceinline__ float rcp_fast(float v) { return __builtin_amdgcn_rcpf(v); }
__device__ __forceinline__ float sigm(float v) { return rcp_fast(1.0f + __expf(-v)); }
__device__ __forceinline__ float tanh_fast(float v) {
    return fmaf(-2.0f, rcp_fast(1.0f + __expf(2.0f * v)), 1.0f);
}

// packed FP32 FMA: acc.lo += a.lo*b.lo; acc.hi += a.hi*b.hi  (one VALU instr)
__device__ __forceinline__ void pk_fma(f32x2& acc, f32x2 a, f32x2 b) {
    asm("v_pk_fma_f32 %0, %1, %2, %0" : "+v"(acc) : "v"(a), "v"(b));
}

// One-block repack (unchanged layout): fold temporal_proj into layer-0 input
// projection; lay LSTM weights in exact consumption order (wave owns 2 units).
__global__ void repack(const float* __restrict__ Wtp,  const float* __restrict__ btp,
                       const float* __restrict__ Wih0, const float* __restrict__ Whh0,
                       const float* __restrict__ bih0, const float* __restrict__ bhh0,
                       const float* __restrict__ Wih1, const float* __restrict__ Whh1,
                       const float* __restrict__ bih1, const float* __restrict__ bhh1,
                       const float* __restrict__ Wfc1, const float* __restrict__ bfc1,
                       const float* __restrict__ Wfc2, const float* __restrict__ bfc2,
                       float* __restrict__ ws)
{
    const int tid = threadIdx.x;  // 256 threads
    if (tid < 128) {
        int k = tid >> 2, g = tid & 3;
        int r = g * 32 + k;                 // PyTorch gate-major row (i,f,g,o)
        float u = 0.f, v = 0.f;
        for (int d = 0; d < 16; ++d) {
            u = fmaf(Wih0[r * 16 + d], Wtp[d], u);
            v = fmaf(Wih0[r * 16 + d], btp[d], v);
        }
        ws[OFF_UV + k * 8 + g]     = u;
        ws[OFF_UV + k * 8 + 4 + g] = v + bih0[r] + bhh0[r];
        ws[OFF_B1 + tid]           = bih1[r] + bhh1[r];   // [k*4+g]
    }
    for (int idx = tid; idx < 4096; idx += 256) {
        int w = idx >> 8, rem = idx & 255;
        int j4 = rem >> 5, rem2 = rem & 31;
        int u = rem2 >> 4, g = (rem2 >> 2) & 3, jj = rem2 & 3;
        int K = w * 2 + u, r = g * 32 + K;
        ws[OFF_W0 + idx] = Whh0[r * 32 + j4 * 4 + jj];
    }
    for (int idx = tid; idx < 8192; idx += 256) {
        int w = idx >> 9, rem = idx & 511;
        int j4 = rem >> 5, rem2 = rem & 31;
        int u = rem2 >> 4, g = (rem2 >> 2) & 3, jj = rem2 & 3;
        int K = w * 2 + u, r = g * 32 + K;
        ws[OFF_W1 + idx] = (j4 < 8) ? Wih1[r * 32 + j4 * 4 + jj]
                                    : Whh1[r * 32 + (j4 - 8) * 4 + jj];
    }
    for (int idx = tid; idx < 512; idx += 256) {
        int m = idx >> 5, j = idx & 31;
        ws[OFF_FC1 + idx] = Wfc1[j * 16 + m];
    }
    if (tid < 16) { ws[OFF_BFC1 + tid] = bfc1[tid]; ws[OFF_FC2 + tid] = Wfc2[tid]; }
    if (tid == 0) ws[OFF_BFC2] = bfc2[0];
}

// Structure identical to R9 (256 nodes/block, 16 waves, wave owns 2 units,
// lane handles 4 nodes, weights LDS-broadcast, h coalesced-transposed in LDS).
// CHANGE: inner dot products use v_pk_fma_f32 packed along the j dimension --
// (q.x,q.y)x(h.x,h.y) and (q.z,q.w)x(h.z,h.w) are naturally adjacent VGPR
// pairs from the b128 reads, so 2 FMAs/lane/instr with zero shuffles. FMA
// issue halves: 3072 -> 1536 instr/wave-step. f32x2 partial-sum pairs per
// (u,g,m), one horizontal add at gate time. Clean A/B on issue- vs
// stall-bound (R9: wall 551us vs ~190us pure-FMA-issue model).
__global__ __launch_bounds__(1024)
void lstm_main(const float* __restrict__ x, const float* __restrict__ ws,
               float* __restrict__ out)
{
    __shared__ __align__(16) float sw[13232];         // 52.9 KB weights
    __shared__ __align__(16) float sh0[8 * 1024];     // 32 KB  [col4][node*4+jj]
    __shared__ __align__(16) float sh1[2 * 8 * 1024]; // 64 KB  [parity][col4][node*4+jj]

    const int tid  = threadIdx.x;
    const int lane = tid & 63;
    const int wv   = __builtin_amdgcn_readfirstlane(tid >> 6);  // 0..15
    const int K0   = wv * 2;
    const int b0   = blockIdx.x * 256;

    for (int i = tid; i < W_TOTAL; i += 1024) sw[i] = ws[i];
    for (int i = tid; i < 8 * 1024; i += 1024) { sh0[i] = 0.f; sh1[i] = 0.f; }

    int xi[4];
#pragma unroll
    for (int m = 0; m < 4; ++m) {
        int n = b0 + lane + 64 * m;
        xi[m] = (n < NN) ? n : 0;
    }

    float c0[2][4], c1[2][4];
#pragma unroll
    for (int u = 0; u < 2; ++u)
#pragma unroll
        for (int m = 0; m < 4; ++m) { c0[u][m] = 0.f; c1[u][m] = 0.f; }

    __syncthreads();

    const float* uvp = sw + OFF_UV + K0 * 8;
    const float* b1p = sw + OFF_B1 + K0 * 4;

    float xc[4], xn[4];
#pragma unroll
    for (int m = 0; m < 4; ++m) xc[m] = x[(size_t)xi[m] * 32 + 20];

#pragma unroll 1
    for (int t = 0; t < SEQ; ++t) {
        const int p = t & 1, np = p ^ 1;
#pragma unroll
        for (int m = 0; m < 4; ++m)
            xn[m] = (t + 1 < SEQ) ? x[(size_t)xi[m] * 32 + 21 + t] : 0.f;

        f32x2 a[2][4][4];   // [u][g][m] packed partial sums (even-j, odd-j)

        // ---------------- layer 0 (reads sh0 old) ----------------
#pragma unroll
        for (int u = 0; u < 2; ++u)
#pragma unroll
            for (int g = 0; g < 4; ++g) {
                const float uu = uvp[u * 8 + g], vv = uvp[u * 8 + 4 + g];
#pragma unroll
                for (int m = 0; m < 4; ++m)
                    a[u][g][m] = (f32x2){fmaf(xc[m], uu, vv), 0.f};
            }
#pragma unroll
        for (int j4 = 0; j4 < 8; ++j4) {
            f32x2 hl[4], hh[4];
#pragma unroll
            for (int m = 0; m < 4; ++m) {
                const f32x4 h = *(const f32x4*)&sh0[j4 * 1024 + (lane + 64 * m) * 4];
                hl[m] = __builtin_shufflevector(h, h, 0, 1);
                hh[m] = __builtin_shufflevector(h, h, 2, 3);
            }
            const float* wp = sw + OFF_W0 + (wv * 8 + j4) * 32;
#pragma unroll
            for (int u = 0; u < 2; ++u)
#pragma unroll
                for (int g = 0; g < 4; ++g) {
                    const f32x4 q = *(const f32x4*)(wp + u * 16 + g * 4); // broadcast
                    const f32x2 ql = __builtin_shufflevector(q, q, 0, 1);
                    const f32x2 qh = __builtin_shufflevector(q, q, 2, 3);
#pragma unroll
                    for (int m = 0; m < 4; ++m) {
                        pk_fma(a[u][g][m], ql, hl[m]);
                        pk_fma(a[u][g][m], qh, hh[m]);
                    }
                }
        }
        float hn[2][4];
#pragma unroll
        for (int u = 0; u < 2; ++u)
#pragma unroll
            for (int m = 0; m < 4; ++m) {
                const float gi = sigm(a[u][0][m].x + a[u][0][m].y);
                const float gf = sigm(a[u][1][m].x + a[u][1][m].y);
                const float gg = tanh_fast(a[u][2][m].x + a[u][2][m].y);
                const float go = sigm(a[u][3][m].x + a[u][3][m].y);
                const float cc = fmaf(gf, c0[u][m], gi * gg);
                c0[u][m] = cc;
                hn[u][m] = go * tanh_fast(cc);
            }
        __syncthreads();   // bar1: all sh0 reads done
#pragma unroll
        for (int u = 0; u < 2; ++u) {
            const int K = K0 + u;
#pragma unroll
            for (int m = 0; m < 4; ++m)
                sh0[(K >> 2) * 1024 + (lane + 64 * m) * 4 + (K & 3)] = hn[u][m];
        }
        __syncthreads();   // bar2: sh0 new visible

        // ---------------- layer 1 (reads sh0 new + sh1[p], writes sh1[np]) ----
#pragma unroll
        for (int u = 0; u < 2; ++u)
#pragma unroll
            for (int g = 0; g < 4; ++g) {
                const float bb = b1p[u * 4 + g];
#pragma unroll
                for (int m = 0; m < 4; ++m) a[u][g][m] = (f32x2){bb, 0.f};
            }
#pragma unroll
        for (int j4 = 0; j4 < 16; ++j4) {
            f32x2 hl[4], hh[4];
#pragma unroll
            for (int m = 0; m < 4; ++m) {
                const int i4 = (lane + 64 * m) * 4;
                const f32x4 h = (j4 < 8)
                    ? *(const f32x4*)&sh0[j4 * 1024 + i4]
                    : *(const f32x4*)&sh1[p * 8192 + (j4 - 8) * 1024 + i4];
                hl[m] = __builtin_shufflevector(h, h, 0, 1);
                hh[m] = __builtin_shufflevector(h, h, 2, 3);
            }
            const float* wp = sw + OFF_W1 + (wv * 16 + j4) * 32;
#pragma unroll
            for (int u = 0; u < 2; ++u)
#pragma unroll
                for (int g = 0; g < 4; ++g) {
                    const f32x4 q = *(const f32x4*)(wp + u * 16 + g * 4); // broadcast
                    const f32x2 ql = __builtin_shufflevector(q, q, 0, 1);
                    const f32x2 qh = __builtin_shufflevector(q, q, 2, 3);
#pragma unroll
                    for (int m = 0; m < 4; ++m) {
                        pk_fma(a[u][g][m], ql, hl[m]);
                        pk_fma(a[u][g][m], qh, hh[m]);
                    }
                }
        }
#pragma unroll
        for (int u = 0; u < 2; ++u) {
            const int K = K0 + u;
#pragma unroll
            for (int m = 0; m < 4; ++m) {
                const float gi = sigm(a[u][0][m].x + a[u][0][m].y);
                const float gf = sigm(a[u][1][m].x + a[u][1][m].y);
                const float gg = tanh_fast(a[u][2][m].x + a[u][2][m].y);
                const float go = sigm(a[u][3][m].x + a[u][3][m].y);
                const float cc = fmaf(gf, c1[u][m], gi * gg);
                c1[u][m] = cc;
                sh1[np * 8192 + (K >> 2) * 1024 + (lane + 64 * m) * 4 + (K & 3)]
                    = go * tanh_fast(cc);
            }
        }
        // no barrier: sh1 parity-buffered; next step's bar1/bar2 order everything
#pragma unroll
        for (int m = 0; m < 4; ++m) xc[m] = xn[m];
    }

    __syncthreads();   // final h1 (parity 0 after t=11) visible

    // -------- fc head: waves 0-3, wave w handles node group m=w ----------
    if (wv < 4) {
        const int node = b0 + lane + 64 * wv;
        const int i4   = (lane + 64 * wv) * 4;
        f32x4 hf[8];
#pragma unroll
        for (int j4 = 0; j4 < 8; ++j4)
            hf[j4] = *(const f32x4*)&sh1[j4 * 1024 + i4];   // parity 0
        float acc2 = sw[OFF_BFC2];
#pragma unroll
        for (int mm = 0; mm < 16; ++mm) {
            const float* fp = sw + OFF_FC1 + mm * 32;
            float y = sw[OFF_BFC1 + mm];
#pragma unroll
            for (int j4 = 0; j4 < 8; ++j4) {
                y = fmaf(fp[j4 * 4 + 0], hf[j4].x, y);
                y = fmaf(fp[j4 * 4 + 1], hf[j4].y, y);
                y = fmaf(fp[j4 * 4 + 2], hf[j4].z, y);
                y = fmaf(fp[j4 * 4 + 3], hf[j4].w, y);
            }
            acc2 = fmaf(fmaxf(y, 0.f), sw[OFF_FC2 + mm], acc2);
        }
        if (node < NN) out[node] = acc2;
    }
}

extern "C" void kernel_launch(void* const* d_in, const int* in_sizes, int n_in,
                              void* d_out, int out_size, void* d_ws, size_t ws_size,
                              hipStream_t stream) {
    (void)in_sizes; (void)n_in; (void)out_size; (void)ws_size;
    const float* x    = (const float*)d_in[0];
    // d_in[1] edge_index and d_in[2..9] (GCN weights) are dead code in the reference
    const float* Wtp  = (const float*)d_in[10];
    const float* btp  = (const float*)d_in[11];
    const float* Wih0 = (const float*)d_in[12];
    const float* Whh0 = (const float*)d_in[13];
    const float* bih0 = (const float*)d_in[14];
    const float* bhh0 = (const float*)d_in[15];
    const float* Wih1 = (const float*)d_in[16];
    const float* Whh1 = (const float*)d_in[17];
    const float* bih1 = (const float*)d_in[18];
    const float* bhh1 = (const float*)d_in[19];
    const float* Wfc1 = (const float*)d_in[20];
    const float* bfc1 = (const float*)d_in[21];
    const float* Wfc2 = (const float*)d_in[22];
    const float* bfc2 = (const float*)d_in[23];
    float* ws  = (float*)d_ws;
    float* out = (float*)d_out;

    hipLaunchKernelGGL(repack, dim3(1), dim3(256), 0, stream,
                       Wtp, btp, Wih0, Whh0, bih0, bhh0,
                       Wih1, Whh1, bih1, bhh1, Wfc1, bfc1, Wfc2, bfc2, ws);
    hipLaunchKernelGGL(lstm_main, dim3((NN + 255) / 256), dim3(1024), 0, stream,
                       x, ws, out);
}

// Round 11
// 247.343 us; speedup vs baseline: 2.0320x; 2.0320x over previous
//
#include <hip/hip_runtime.h>

#define NN  100000
#define SEQ 12

typedef float f32x4 __attribute__((ext_vector_type(4)));
typedef short s16x8 __attribute__((ext_vector_type(8)));

// ---- d_ws float offsets ----
#define OFF_U    0        // [tau 0..7][lane][reg] f32 : u for C-row  (2048)
#define OFF_V    2048     // [tau][lane][reg] v + bih0 + bhh0          (2048)
#define OFF_B1F  4096     // [tau][lane][reg] bih1 + bhh1              (2048)
#define OFF_FC1  6144     // [m 0..15][j 0..31] W_fc1^T                (512)
#define OFF_BFC1 6656     // [16]
#define OFF_FC2  6672     // [16]
#define OFF_BFC2 6688     // [1]
#define OFF_A    6720     // short region: A0 frags [0,8192) shorts, A1 frags [8192,24576)

__device__ __forceinline__ float rcp_fast(float v) { return __builtin_amdgcn_rcpf(v); }
__device__ __forceinline__ float sigm(float v) { return rcp_fast(1.0f + __expf(-v)); }
__device__ __forceinline__ float tanh_fast(float v) {
    return fmaf(-2.0f, rcp_fast(1.0f + __expf(2.0f * v)), 1.0f);
}
__device__ __forceinline__ unsigned short f2bf(float f) {   // RN-even fp32 -> bf16
    unsigned u = __float_as_uint(f);
    u = u + 0x7FFFu + ((u >> 16) & 1u);
    return (unsigned short)(u >> 16);
}
__device__ __forceinline__ float bf2f(unsigned short h) {
    return __uint_as_float(((unsigned)h) << 16);
}

#define MF(a, b, c) __builtin_amdgcn_mfma_f32_16x16x32_bf16((a), (b), (c), 0, 0, 0)

// Repack: gate-rows reordered unit-interleaved r' = 4k+g (so C-frag lane holds
// i,f,g,o of ONE unit in its 4 regs); weights split hi/lo bf16 and emitted as
// ready-to-load A-fragments (A row = lane&15, k = (lane>>4)*8+e — the same k
// convention used when packing H into B-frags, so any HW k-permutation cancels).
__global__ void repack(const float* __restrict__ Wtp,  const float* __restrict__ btp,
                       const float* __restrict__ Wih0, const float* __restrict__ Whh0,
                       const float* __restrict__ bih0, const float* __restrict__ bhh0,
                       const float* __restrict__ Wih1, const float* __restrict__ Whh1,
                       const float* __restrict__ bih1, const float* __restrict__ bhh1,
                       const float* __restrict__ Wfc1, const float* __restrict__ bfc1,
                       const float* __restrict__ Wfc2, const float* __restrict__ bfc2,
                       float* __restrict__ ws)
{
    const int tid = threadIdx.x;  // 256
    // u/v/b1 fragments: indexed by C-frag rows (row = (lane>>4)*4 + reg)
    for (int idx = tid; idx < 2048; idx += 256) {
        int tau = idx >> 8, lane = (idx >> 2) & 63, reg = idx & 3;
        int grow = 16 * tau + (lane >> 4) * 4 + reg;      // r' = 4k+g
        int k = grow >> 2, g = grow & 3;
        int orig = g * 32 + k;                            // PyTorch row
        float u = 0.f, v = 0.f;
        for (int d = 0; d < 16; ++d) {
            u = fmaf(Wih0[orig * 16 + d], Wtp[d], u);
            v = fmaf(Wih0[orig * 16 + d], btp[d], v);
        }
        ws[OFF_U + idx]   = u;
        ws[OFF_V + idx]   = v + bih0[orig] + bhh0[orig];
        ws[OFF_B1F + idx] = bih1[orig] + bhh1[orig];
    }
    short* wsS = (short*)(ws + OFF_A);
    // A0 (layer-0 Whh, K=32): [tau][term][lane][e]
    for (int idx = tid; idx < 8192; idx += 256) {
        int tau = idx >> 10, t = (idx >> 9) & 1, lane = (idx >> 3) & 63, e = idx & 7;
        int rl = lane & 15;
        int orig = (rl & 3) * 32 + 4 * tau + (rl >> 2);   // A row = lane&15 of r'=4k+g order
        int j = (lane >> 4) * 8 + e;
        float f = Whh0[orig * 32 + j];
        unsigned short hi = f2bf(f);
        wsS[idx] = (short)(t == 0 ? hi : f2bf(f - bf2f(hi)));
    }
    // A1 ([Wih1|Whh1], K=64 as 2 kappa-tiles): [tau][kappa][term][lane][e]
    for (int idx = tid; idx < 16384; idx += 256) {
        int tau = idx >> 11, kap = (idx >> 10) & 1, t = (idx >> 9) & 1;
        int lane = (idx >> 3) & 63, e = idx & 7;
        int rl = lane & 15;
        int orig = (rl & 3) * 32 + 4 * tau + (rl >> 2);
        int j = (lane >> 4) * 8 + e;
        float f = kap ? Whh1[orig * 32 + j] : Wih1[orig * 32 + j];
        unsigned short hi = f2bf(f);
        wsS[8192 + idx] = (short)(t == 0 ? hi : f2bf(f - bf2f(hi)));
    }
    for (int idx = tid; idx < 512; idx += 256) {
        int m = idx >> 5, j = idx & 31;
        ws[OFF_FC1 + idx] = Wfc1[j * 16 + m];
    }
    if (tid < 16) { ws[OFF_BFC1 + tid] = bfc1[tid]; ws[OFF_FC2 + tid] = Wfc2[tid]; }
    if (tid == 0) ws[OFF_BFC2] = bfc2[0];
}

// MFMA LSTM: 256 nodes/block, 16 waves; wave w -> gate-tile tau=w>>1 (units
// 4tau..4tau+3), node-half w&1 (8 node-tiles of 16). Weights live in 24
// persistent VGPRs as bf16 hi/lo A-frags (zero LDS weight traffic — R10
// evidence: LDS pipe was the ~560us wall, 3072 broadcast reads/CU/step).
// h exchanged via LDS as bf16 hi/lo B-frags; fp32 accuracy from the 4-product
// 2-term split (err ~2^-17). C-frag (m89: col=lane&15, row=(lane>>4)*4+reg)
// with r'=4k+g row order => lane's 4 acc regs = i,f,g,o of unit 4tau+(lane>>4)
// for node 16nu+col: gates fully lane-local. 2 barriers/step.
// LDS: B-buffers 128KB (Bh0/Bh1 x parity x hi/lo) + x 12KB = 140KB -> 1 blk/CU.
__global__ __launch_bounds__(1024)
void lstm_mfma(const float* __restrict__ x, const float* __restrict__ ws,
               float* __restrict__ out)
{
    __shared__ short sB[65536];      // Bh0: hw [0,32768) ; Bh1: hw [32768,65536)
    __shared__ float sx[SEQ][256];   // [t][node]

    const int tid  = threadIdx.x;
    const int lane = tid & 63;
    const int w    = __builtin_amdgcn_readfirstlane(tid >> 6);  // 0..15
    const int tau  = w >> 1, half = w & 1;
    const int lg   = lane >> 4, col = lane & 15;
    const int ku   = 4 * tau + lg;            // this lane's unit
    const int b0   = blockIdx.x * 256;

    // stage x
    for (int i = tid; i < SEQ * 256; i += 1024) {
        int t = i >> 8, nd = i & 255;
        int n = b0 + nd;
        sx[t][nd] = (n < NN) ? x[(size_t)n * 32 + 20 + t] : 0.f;
    }
    // zero parity-0 h buffers (h0-old = h1-old = 0 at t=0)
    int* sB32 = (int*)sB;
    for (int i = tid; i < 8192; i += 1024) { sB32[i] = 0; sB32[16384 + i] = 0; }

    // persistent fragments
    const f32x4 uf  = *(const f32x4*)(ws + OFF_U   + (tau * 64 + lane) * 4);
    const f32x4 vf  = *(const f32x4*)(ws + OFF_V   + (tau * 64 + lane) * 4);
    const f32x4 b1f = *(const f32x4*)(ws + OFF_B1F + (tau * 64 + lane) * 4);
    const short* AS  = (const short*)(ws + OFF_A);
    const s16x8 A0h  = *(const s16x8*)(AS + ((tau * 2 + 0) * 64 + lane) * 8);
    const s16x8 A0l  = *(const s16x8*)(AS + ((tau * 2 + 1) * 64 + lane) * 8);
    const short* AS1 = AS + 8192;
    const s16x8 A10h = *(const s16x8*)(AS1 + ((tau * 4 + 0) * 64 + lane) * 8);
    const s16x8 A10l = *(const s16x8*)(AS1 + ((tau * 4 + 1) * 64 + lane) * 8);
    const s16x8 A11h = *(const s16x8*)(AS1 + ((tau * 4 + 2) * 64 + lane) * 8);
    const s16x8 A11l = *(const s16x8*)(AS1 + ((tau * 4 + 3) * 64 + lane) * 8);

    float c0[8], c1[8];
#pragma unroll
    for (int i = 0; i < 8; ++i) { c0[i] = 0.f; c1[i] = 0.f; }

    __syncthreads();

#pragma unroll 1
    for (int t = 0; t < SEQ; ++t) {
        const int p = t & 1, np = p ^ 1;

        // ---------- layer 0: reads Bh0[p], writes Bh0[np] ----------
#pragma unroll 2
        for (int i = 0; i < 8; ++i) {
            const int node = (half * 8 + i) * 16 + col;
            const float xv = sx[t][node];
            f32x4 acc;
            acc[0] = fmaf(uf[0], xv, vf[0]);
            acc[1] = fmaf(uf[1], xv, vf[1]);
            acc[2] = fmaf(uf[2], xv, vf[2]);
            acc[3] = fmaf(uf[3], xv, vf[3]);
            const s16x8 bh = *(const s16x8*)&sB[((p * 2 + 0) * 4 + lg) * 2048 + node * 8];
            acc = MF(A0h, bh, acc);
            acc = MF(A0l, bh, acc);
            const s16x8 bl = *(const s16x8*)&sB[((p * 2 + 1) * 4 + lg) * 2048 + node * 8];
            acc = MF(A0h, bl, acc);
            acc = MF(A0l, bl, acc);
            const float gi = sigm(acc[0]), gf = sigm(acc[1]);
            const float gg = tanh_fast(acc[2]), go = sigm(acc[3]);
            const float cc = fmaf(gf, c0[i], gi * gg);
            c0[i] = cc;
            const float h = go * tanh_fast(cc);
            const unsigned short hh = f2bf(h);
            const unsigned short hl = f2bf(h - bf2f(hh));
            sB[((np * 2 + 0) * 4 + (ku >> 3)) * 2048 + node * 8 + (ku & 7)] = (short)hh;
            sB[((np * 2 + 1) * 4 + (ku >> 3)) * 2048 + node * 8 + (ku & 7)] = (short)hl;
        }
        __syncthreads();   // bar1: h0-new complete & visible

        // ---------- layer 1: reads Bh0[np] + Bh1[p], writes Bh1[np] ----------
#pragma unroll 2
        for (int i = 0; i < 8; ++i) {
            const int node = (half * 8 + i) * 16 + col;
            f32x4 acc;
            acc[0] = b1f[0]; acc[1] = b1f[1]; acc[2] = b1f[2]; acc[3] = b1f[3];
            const s16x8 b0h = *(const s16x8*)&sB[((np * 2 + 0) * 4 + lg) * 2048 + node * 8];
            acc = MF(A10h, b0h, acc);
            acc = MF(A10l, b0h, acc);
            const s16x8 b0l = *(const s16x8*)&sB[((np * 2 + 1) * 4 + lg) * 2048 + node * 8];
            acc = MF(A10h, b0l, acc);
            acc = MF(A10l, b0l, acc);
            const s16x8 b1h = *(const s16x8*)&sB[32768 + ((p * 2 + 0) * 4 + lg) * 2048 + node * 8];
            acc = MF(A11h, b1h, acc);
            acc = MF(A11l, b1h, acc);
            const s16x8 b1l = *(const s16x8*)&sB[32768 + ((p * 2 + 1) * 4 + lg) * 2048 + node * 8];
            acc = MF(A11h, b1l, acc);
            acc = MF(A11l, b1l, acc);
            const float gi = sigm(acc[0]), gf = sigm(acc[1]);
            const float gg = tanh_fast(acc[2]), go = sigm(acc[3]);
            const float cc = fmaf(gf, c1[i], gi * gg);
            c1[i] = cc;
            const float h = go * tanh_fast(cc);
            const unsigned short hh = f2bf(h);
            const unsigned short hl = f2bf(h - bf2f(hh));
            sB[32768 + ((np * 2 + 0) * 4 + (ku >> 3)) * 2048 + node * 8 + (ku & 7)] = (short)hh;
            sB[32768 + ((np * 2 + 1) * 4 + (ku >> 3)) * 2048 + node * 8 + (ku & 7)] = (short)hl;
            if (t == SEQ - 1)   // final h1 fp32 into Bh0[p=1] region (readers done at bar1)
                ((float*)sB)[8192 + node * 32 + ku] = h;
        }
        __syncthreads();   // bar2: h1-new complete & visible
    }

    // ---------- fc head: waves 0-3, one node per lane ----------
    if (w < 4) {
        const int nd = w * 64 + lane;
        const float* hf = (const float*)sB + 8192 + nd * 32;
        float h[32];
#pragma unroll
        for (int j = 0; j < 32; ++j) h[j] = hf[j];
        float acc2 = ws[OFF_BFC2];
#pragma unroll
        for (int m = 0; m < 16; ++m) {
            const float* fp = ws + OFF_FC1 + m * 32;   // uniform -> s_load
            float y = ws[OFF_BFC1 + m];
#pragma unroll
            for (int j = 0; j < 32; ++j) y = fmaf(fp[j], h[j], y);
            acc2 = fmaf(fmaxf(y, 0.f), ws[OFF_FC2 + m], acc2);
        }
        if (b0 + nd < NN) out[b0 + nd] = acc2;
    }
}

extern "C" void kernel_launch(void* const* d_in, const int* in_sizes, int n_in,
                              void* d_out, int out_size, void* d_ws, size_t ws_size,
                              hipStream_t stream) {
    (void)in_sizes; (void)n_in; (void)out_size; (void)ws_size;
    const float* x    = (const float*)d_in[0];
    // d_in[1] edge_index and d_in[2..9] (GCN weights) are dead code in the reference
    const float* Wtp  = (const float*)d_in[10];
    const float* btp  = (const float*)d_in[11];
    const float* Wih0 = (const float*)d_in[12];
    const float* Whh0 = (const float*)d_in[13];
    const float* bih0 = (const float*)d_in[14];
    const float* bhh0 = (const float*)d_in[15];
    const float* Wih1 = (const float*)d_in[16];
    const float* Whh1 = (const float*)d_in[17];
    const float* bih1 = (const float*)d_in[18];
    const float* bhh1 = (const float*)d_in[19];
    const float* Wfc1 = (const float*)d_in[20];
    const float* bfc1 = (const float*)d_in[21];
    const float* Wfc2 = (const float*)d_in[22];
    const float* bfc2 = (const float*)d_in[23];
    float* ws  = (float*)d_ws;
    float* out = (float*)d_out;

    hipLaunchKernelGGL(repack, dim3(1), dim3(256), 0, stream,
                       Wtp, btp, Wih0, Whh0, bih0, bhh0,
                       Wih1, Whh1, bih1, bhh1, Wfc1, bfc1, Wfc2, bfc2, ws);
    hipLaunchKernelGGL(lstm_mfma, dim3((NN + 255) / 256), dim3(1024), 0, stream,
                       x, ws, out);
}

// Round 12
// 160.414 us; speedup vs baseline: 3.1331x; 1.5419x over previous
//
#include <hip/hip_runtime.h>

#define NN   100000
#define SEQ  12
#define NPB  208                     // nodes per block (13 MFMA node-tiles)
#define XSTR 256                     // sx row stride
#define RSTR 1664                    // B row stride in shorts (NPB*8)
#define GRID ((NN + NPB - 1) / NPB)  // 481 -> exactly 2 dispatch rounds

typedef float f32x4 __attribute__((ext_vector_type(4)));
typedef short s16x8 __attribute__((ext_vector_type(8)));

// ---- d_ws float offsets ----
#define OFF_U    0        // [tau][lane][reg] scaled u
#define OFF_V    2048     // [tau][lane][reg] scaled (v + bih0 + bhh0)
#define OFF_B1F  4096     // [tau][lane][reg] scaled (bih1 + bhh1)
#define OFF_FC1  6144     // [m][j] W_fc1^T
#define OFF_BFC1 6656
#define OFF_FC2  6672
#define OFF_BFC2 6688
#define OFF_A    6720     // shorts: A0 [0,8192), A1 [8192,24576)

#define L2E  1.4426950408889634f
#define L2E2 2.8853900817779268f

#if defined(__has_builtin)
#if __has_builtin(__builtin_amdgcn_exp2f)
#define EXP2(x) __builtin_amdgcn_exp2f(x)
#endif
#endif
#ifndef EXP2
#define EXP2(x) exp2f(x)
#endif

__device__ __forceinline__ float rcp_fast(float v) { return __builtin_amdgcn_rcpf(v); }
// preact pre-scaled by -log2e at repack: sigm(z) = rcp(1+exp2(-log2e*z))
__device__ __forceinline__ float sigm_p(float a) { return rcp_fast(1.0f + EXP2(a)); }
// preact pre-scaled by +2log2e: tanh(z) = 1 - 2*rcp(1+exp2(2log2e*z))
__device__ __forceinline__ float tanh_p(float a) {
    return fmaf(-2.0f, rcp_fast(1.0f + EXP2(a)), 1.0f);
}
__device__ __forceinline__ unsigned short f2bf(float f) {   // RNE fp32->bf16 (repack)
    unsigned u = __float_as_uint(f);
    u = u + 0x7FFFu + ((u >> 16) & 1u);
    return (unsigned short)(u >> 16);
}
__device__ __forceinline__ float bf2f(unsigned short h) {
    return __uint_as_float(((unsigned)h) << 16);
}
// hw packed cvt for the runtime h hi/lo split (self-correcting: rounding mode
// of the hi term is compensated by the lo term)
__device__ __forceinline__ void hsplit(float h, unsigned& uh, unsigned& ul) {
    asm("v_cvt_pk_bf16_f32 %0, %1, %1" : "=v"(uh) : "v"(h));
    const float lo = h - __uint_as_float(uh << 16);
    asm("v_cvt_pk_bf16_f32 %0, %1, %1" : "=v"(ul) : "v"(lo));
}

#define MF(a, b, c) __builtin_amdgcn_mfma_f32_16x16x32_bf16((a), (b), (c), 0, 0, 0)

// Repack: r'=4k+g row order; gate-scale folded into ALL preact terms
// (i,f,o rows * -log2e ; g rows * +2log2e); weights hi/lo bf16 A-fragments.
__global__ void repack(const float* __restrict__ Wtp,  const float* __restrict__ btp,
                       const float* __restrict__ Wih0, const float* __restrict__ Whh0,
                       const float* __restrict__ bih0, const float* __restrict__ bhh0,
                       const float* __restrict__ Wih1, const float* __restrict__ Whh1,
                       const float* __restrict__ bih1, const float* __restrict__ bhh1,
                       const float* __restrict__ Wfc1, const float* __restrict__ bfc1,
                       const float* __restrict__ Wfc2, const float* __restrict__ bfc2,
                       float* __restrict__ ws)
{
    const int tid = threadIdx.x;  // 256
    for (int idx = tid; idx < 2048; idx += 256) {
        int tau = idx >> 8, lane = (idx >> 2) & 63, reg = idx & 3;
        int grow = 16 * tau + (lane >> 4) * 4 + reg;
        int k = grow >> 2, g = grow & 3;
        int orig = g * 32 + k;
        float sg = (g == 2) ? L2E2 : -L2E;
        float u = 0.f, v = 0.f;
        for (int d = 0; d < 16; ++d) {
            u = fmaf(Wih0[orig * 16 + d], Wtp[d], u);
            v = fmaf(Wih0[orig * 16 + d], btp[d], v);
        }
        ws[OFF_U + idx]   = sg * u;
        ws[OFF_V + idx]   = sg * (v + bih0[orig] + bhh0[orig]);
        ws[OFF_B1F + idx] = sg * (bih1[orig] + bhh1[orig]);
    }
    short* wsS = (short*)(ws + OFF_A);
    for (int idx = tid; idx < 8192; idx += 256) {
        int tau = idx >> 10, t = (idx >> 9) & 1, lane = (idx >> 3) & 63, e = idx & 7;
        int rl = lane & 15, g = rl & 3;
        int orig = g * 32 + 4 * tau + (rl >> 2);
        int j = (lane >> 4) * 8 + e;
        float sg = (g == 2) ? L2E2 : -L2E;
        float f = sg * Whh0[orig * 32 + j];
        unsigned short hi = f2bf(f);
        wsS[idx] = (short)(t == 0 ? hi : f2bf(f - bf2f(hi)));
    }
    for (int idx = tid; idx < 16384; idx += 256) {
        int tau = idx >> 11, kap = (idx >> 10) & 1, t = (idx >> 9) & 1;
        int lane = (idx >> 3) & 63, e = idx & 7;
        int rl = lane & 15, g = rl & 3;
        int orig = g * 32 + 4 * tau + (rl >> 2);
        int j = (lane >> 4) * 8 + e;
        float sg = (g == 2) ? L2E2 : -L2E;
        float f = sg * (kap ? Whh1[orig * 32 + j] : Wih1[orig * 32 + j]);
        unsigned short hi = f2bf(f);
        wsS[8192 + idx] = (short)(t == 0 ? hi : f2bf(f - bf2f(hi)));
    }
    for (int idx = tid; idx < 512; idx += 256) {
        int m = idx >> 5, j = idx & 31;
        ws[OFF_FC1 + idx] = Wfc1[j * 16 + m];
    }
    if (tid < 16) { ws[OFF_BFC1 + tid] = bfc1[tid]; ws[OFF_FC2 + tid] = Wfc2[tid]; }
    if (tid == 0) ws[OFF_BFC2] = bfc2[0];
}

// One LSTM time-step, parity P compile-time (all LDS addrs = base + immediate).
// 3-product bf16x2 split (hi*hi + lo*hi + hi*lo; ll term ~2^-18 dropped).
template<int P, int NI, int TILE0>
__device__ __forceinline__ void lstm_step(
    short* __restrict__ B0, short* __restrict__ B1,
    const float*& sxp, float* __restrict__ fin,
    f32x4 uf, f32x4 vf, f32x4 b1f,
    s16x8 A0h, s16x8 A0l, s16x8 A10h, s16x8 A10l, s16x8 A11h, s16x8 A11l,
    float (&c0)[NI], float (&c1)[NI],
    int col, int lg, int ku, bool last)
{
    constexpr int NP = P ^ 1;
    const int nb = (TILE0 * 16 + col) * 8;
    const short* rb0 = B0 + lg * RSTR + nb;
    const short* rb1 = B1 + lg * RSTR + nb;
    short* wb0 = B0 + (ku >> 3) * RSTR + nb + (ku & 7);
    short* wb1 = B1 + (ku >> 3) * RSTR + nb + (ku & 7);

    // ---- layer 0: reads Bh0[P], writes Bh0[NP] ----
#pragma unroll
    for (int i = 0; i < NI; ++i) {
        const float xv = sxp[i * 16];
        f32x4 acc = { fmaf(uf[0], xv, vf[0]), fmaf(uf[1], xv, vf[1]),
                      fmaf(uf[2], xv, vf[2]), fmaf(uf[3], xv, vf[3]) };
        const s16x8 bh = *(const s16x8*)(rb0 + (P * 8) * RSTR + i * 128);
        const s16x8 bl = *(const s16x8*)(rb0 + (P * 8 + 4) * RSTR + i * 128);
        acc = MF(A0h, bh, acc);
        acc = MF(A0l, bh, acc);
        acc = MF(A0h, bl, acc);
        const float gi = sigm_p(acc[0]);
        const float gf = sigm_p(acc[1]);
        const float gg = tanh_p(acc[2]);
        const float go = sigm_p(acc[3]);
        const float cc = fmaf(gf, c0[i], gi * gg);
        c0[i] = cc;
        const float h = go * tanh_p(L2E2 * cc);
        unsigned uh, ul; hsplit(h, uh, ul);
        wb0[(NP * 8) * RSTR + i * 128]     = (short)uh;
        wb0[(NP * 8 + 4) * RSTR + i * 128] = (short)ul;
    }
    __syncthreads();   // bar1: h0-new complete

    // ---- layer 1: reads Bh0[NP] + Bh1[P], writes Bh1[NP] ----
#pragma unroll
    for (int i = 0; i < NI; ++i) {
        f32x4 acc = { b1f[0], b1f[1], b1f[2], b1f[3] };
        const s16x8 b0h = *(const s16x8*)(rb0 + (NP * 8) * RSTR + i * 128);
        const s16x8 b0l = *(const s16x8*)(rb0 + (NP * 8 + 4) * RSTR + i * 128);
        const s16x8 b1h = *(const s16x8*)(rb1 + (P * 8) * RSTR + i * 128);
        const s16x8 b1l = *(const s16x8*)(rb1 + (P * 8 + 4) * RSTR + i * 128);
        acc = MF(A10h, b0h, acc);
        acc = MF(A10l, b0h, acc);
        acc = MF(A10h, b0l, acc);
        acc = MF(A11h, b1h, acc);
        acc = MF(A11l, b1h, acc);
        acc = MF(A11h, b1l, acc);
        const float gi = sigm_p(acc[0]);
        const float gf = sigm_p(acc[1]);
        const float gg = tanh_p(acc[2]);
        const float go = sigm_p(acc[3]);
        const float cc = fmaf(gf, c1[i], gi * gg);
        c1[i] = cc;
        const float h = go * tanh_p(L2E2 * cc);
        if (last) {
            // transposed [unit][node] so fc reads are conflict-free; region =
            // Bh0 parity-1 rows (its readers finished before bar1 of this step)
            fin[ku * NPB + TILE0 * 16 + col + i * 16] = h;
        } else {
            unsigned uh, ul; hsplit(h, uh, ul);
            wb1[(NP * 8) * RSTR + i * 128]     = (short)uh;
            wb1[(NP * 8 + 4) * RSTR + i * 128] = (short)ul;
        }
    }
    __syncthreads();   // bar2: phase complete
    sxp += XSTR;
}

template<int NI, int TILE0>
__device__ __forceinline__ void run_all(
    short* B0, short* B1, const float* sxbase, float* fin,
    f32x4 uf, f32x4 vf, f32x4 b1f,
    s16x8 A0h, s16x8 A0l, s16x8 A10h, s16x8 A10l, s16x8 A11h, s16x8 A11l,
    int col, int lg, int ku)
{
    float c0[NI], c1[NI];
#pragma unroll
    for (int i = 0; i < NI; ++i) { c0[i] = 0.f; c1[i] = 0.f; }
    const float* sxp = sxbase + TILE0 * 16 + col;
#pragma unroll 1
    for (int tt = 0; tt < SEQ / 2; ++tt) {
        lstm_step<0, NI, TILE0>(B0, B1, sxp, fin, uf, vf, b1f,
                                A0h, A0l, A10h, A10l, A11h, A11l,
                                c0, c1, col, lg, ku, false);
        lstm_step<1, NI, TILE0>(B0, B1, sxp, fin, uf, vf, b1f,
                                A0h, A0l, A10h, A10l, A11h, A11l,
                                c0, c1, col, lg, ku, tt == SEQ / 2 - 1);
    }
}

// 208 nodes/block (13 tiles; waves split 7/6), 16 waves, 481 blocks -> exactly
// 2 dispatch rounds (R11: 391 blocks = 1.53 rounds but 2-round makespan = 24%
// tail waste). Weights persistent in VGPR A-frags; h via LDS bf16 hi/lo.
__global__ __launch_bounds__(1024)
void lstm_mfma(const float* __restrict__ x, const float* __restrict__ ws,
               float* __restrict__ out)
{
    __shared__ short sB[2 * 16 * RSTR];   // Bh0 + Bh1, 104 KB
    __shared__ float sx[SEQ][XSTR];       // 12 KB

    const int tid  = threadIdx.x;
    const int lane = tid & 63;
    const int w    = __builtin_amdgcn_readfirstlane(tid >> 6);  // 0..15
    const int tau  = w >> 1, half = w & 1;
    const int lg   = lane >> 4, col = lane & 15;
    const int ku   = 4 * tau + lg;
    const int b0   = blockIdx.x * NPB;

    for (int i = tid; i < SEQ * XSTR; i += 1024) {
        int t = i >> 8, nd = i & 255;
        int n = b0 + nd;
        sx[t][nd] = (nd < NPB && n < NN) ? x[(size_t)n * 32 + 20 + t] : 0.f;
    }
    int* z = (int*)sB;
    for (int i = tid; i < 16 * RSTR; i += 1024) z[i] = 0;

    const f32x4 uf  = *(const f32x4*)(ws + OFF_U   + (tau * 64 + lane) * 4);
    const f32x4 vf  = *(const f32x4*)(ws + OFF_V   + (tau * 64 + lane) * 4);
    const f32x4 b1f = *(const f32x4*)(ws + OFF_B1F + (tau * 64 + lane) * 4);
    const short* AS  = (const short*)(ws + OFF_A);
    const s16x8 A0h  = *(const s16x8*)(AS + ((tau * 2 + 0) * 64 + lane) * 8);
    const s16x8 A0l  = *(const s16x8*)(AS + ((tau * 2 + 1) * 64 + lane) * 8);
    const short* AS1 = AS + 8192;
    const s16x8 A10h = *(const s16x8*)(AS1 + ((tau * 4 + 0) * 64 + lane) * 8);
    const s16x8 A10l = *(const s16x8*)(AS1 + ((tau * 4 + 1) * 64 + lane) * 8);
    const s16x8 A11h = *(const s16x8*)(AS1 + ((tau * 4 + 2) * 64 + lane) * 8);
    const s16x8 A11l = *(const s16x8*)(AS1 + ((tau * 4 + 3) * 64 + lane) * 8);

    short* B0 = sB;
    short* B1 = sB + 16 * RSTR;
    float* fin = (float*)(sB + 8 * RSTR);   // Bh0 parity-1 region, [unit][node]

    __syncthreads();

    if (half == 0)
        run_all<7, 0>(B0, B1, &sx[0][0], fin, uf, vf, b1f,
                      A0h, A0l, A10h, A10l, A11h, A11l, col, lg, ku);
    else
        run_all<6, 7>(B0, B1, &sx[0][0], fin, uf, vf, b1f,
                      A0h, A0l, A10h, A10l, A11h, A11l, col, lg, ku);

    // ---- fc head (last step ended with __syncthreads) ----
    if (w < 4) {
        const int nd = w * 64 + lane;
        if (nd < NPB) {
            float acc2 = ws[OFF_BFC2];
#pragma unroll
            for (int m = 0; m < 16; ++m) {
                const float* fp = ws + OFF_FC1 + m * 32;   // uniform -> s_load
                float y = ws[OFF_BFC1 + m];
#pragma unroll
                for (int j = 0; j < 32; ++j)
                    y = fmaf(fp[j], fin[j * NPB + nd], y);
                acc2 = fmaf(fmaxf(y, 0.f), ws[OFF_FC2 + m], acc2);
            }
            if (b0 + nd < NN) out[b0 + nd] = acc2;
        }
    }
}

extern "C" void kernel_launch(void* const* d_in, const int* in_sizes, int n_in,
                              void* d_out, int out_size, void* d_ws, size_t ws_size,
                              hipStream_t stream) {
    (void)in_sizes; (void)n_in; (void)out_size; (void)ws_size;
    const float* x    = (const float*)d_in[0];
    // d_in[1] edge_index and d_in[2..9] (GCN weights) are dead code in the reference
    const float* Wtp  = (const float*)d_in[10];
    const float* btp  = (const float*)d_in[11];
    const float* Wih0 = (const float*)d_in[12];
    const float* Whh0 = (const float*)d_in[13];
    const float* bih0 = (const float*)d_in[14];
    const float* bhh0 = (const float*)d_in[15];
    const float* Wih1 = (const float*)d_in[16];
    const float* Whh1 = (const float*)d_in[17];
    const float* bih1 = (const float*)d_in[18];
    const float* bhh1 = (const float*)d_in[19];
    const float* Wfc1 = (const float*)d_in[20];
    const float* bfc1 = (const float*)d_in[21];
    const float* Wfc2 = (const float*)d_in[22];
    const float* bfc2 = (const float*)d_in[23];
    float* ws  = (float*)d_ws;
    float* out = (float*)d_out;

    hipLaunchKernelGGL(repack, dim3(1), dim3(256), 0, stream,
                       Wtp, btp, Wih0, Whh0, bih0, bhh0,
                       Wih1, Whh1, bih1, bhh1, Wfc1, bfc1, Wfc2, bfc2, ws);
    hipLaunchKernelGGL(lstm_mfma, dim3(GRID), dim3(1024), 0, stream,
                       x, ws, out);
}